// Round 4
// baseline (1677.075 us; speedup 1.0000x reference)
//
#include <hip/hip_runtime.h>
#include <cstdint>
#include <cstddef>

// ---------------- problem dims ----------------
#define TSTEPS 256
#define BATCH  64
#define OBSD   512
#define HIDD   1024
#define NACT   128
#define TOK    (TSTEPS*BATCH)   // 16384

// fp32 output element offsets
static constexpr size_t O_PROBS = 0;
static constexpr size_t O_LOGPA = (size_t)TOK * NACT;
static constexpr size_t O_ENT   = O_LOGPA + TOK;
static constexpr size_t O_VAL   = O_ENT + TOK;
static constexpr size_t O_HT    = O_VAL + TOK;
static constexpr size_t O_CT    = O_HT + (size_t)BATCH * HIDD;

// bf16 weight/activation pool offsets (elements)
static constexpr size_t OX     = 0;
static constexpr size_t OCOVH  = 8388608;
static constexpr size_t OSNW1  = 10485760;
static constexpr size_t OSNW2  = 11010048;
static constexpr size_t OWIH   = 12058624;
static constexpr size_t OWHH   = 16252928;
static constexpr size_t OACW1  = 20447232;   // ac|cw|cr contiguous -> one N=3072 GEMM
static constexpr size_t OCWW1  = 21495808;
static constexpr size_t OCRW1  = 22544384;
static constexpr size_t OACW2  = 23592960;
static constexpr size_t OCWW2  = 23724032;
static constexpr size_t OCOVW1 = 23855104;
static constexpr size_t OCOVW2 = 23986176;
static constexpr size_t OCRW2  = 24117248;
static constexpr size_t WBUFSZ = 24118272;

using bf16x8 = __attribute__((ext_vector_type(8))) short;
using f32x4  = __attribute__((ext_vector_type(4))) float;

// ---------------- device buffers (all resolved in device code) ----------------
__device__ __align__(16) unsigned short g_wbuf[WBUFSZ];
__device__ __align__(16) unsigned short g_hid1[(size_t)TOK*HIDD];
__device__ __align__(16) unsigned short g_hid [(size_t)TOK*HIDD];
__device__ __align__(16) float          g_xgf [(size_t)TOK*4*HIDD];
__device__ __align__(16) unsigned short g_hid2[(size_t)64*TOK*16];   // blocked hidden [cb][token][16]
__device__ __align__(16) unsigned short g_t3[(size_t)TOK*3*HIDD];    // [TOK][3072] ac|cw|cr
__device__ __align__(16) unsigned short g_aco[(size_t)TOK*NACT];
__device__ __align__(16) unsigned short g_cwo[(size_t)TOK*NACT];
__device__ __align__(16) unsigned short g_covo[(size_t)TOK*NACT];
// blocked h ping-pong: [parity][group(4)][shard(64)][row(16)][col(16)] bf16
__device__ __align__(16) unsigned short g_hp2[2*64*1024];
__device__ float g_ht[BATCH*HIDD];
__device__ float g_ct[BATCH*HIDD];
__device__ int g_isf32;
// flag-based step barrier: one monotonic epoch flag per WG (256 WGs).
// Values persist across launches/graph replays; g_fepoch is bumped by +512
// each launch (detect_dtype) so every launch's targets exceed all stale values.
__device__ unsigned g_flags[256];
__device__ unsigned g_fepoch;

__device__ __forceinline__ unsigned short* dev_buf(int id){
  switch(id){
    case 1:  return g_hid1;
    case 2:  return g_hid;
    case 3:  return g_hid2;
    case 4:  return g_t3;
    case 5:  return g_aco;
    case 6:  return g_cwo;
    case 7:  return g_covo;
    case 8:  return (unsigned short*)g_xgf;
    case 9:  return g_t3 + 1024;          // cw slice (row-interleaved, lda 3072)
    case 10: return g_t3 + 2048;          // cr slice
    case 11: return g_wbuf + OX;
    case 12: return g_wbuf + OCOVH;
    case 13: return g_wbuf + OSNW1;
    case 14: return g_wbuf + OSNW2;
    case 15: return g_wbuf + OWIH;
    case 16: return g_wbuf + OWHH;
    case 17: return g_wbuf + OACW1;       // 3072-row fused head weight
    case 20: return g_wbuf + OACW2;
    case 21: return g_wbuf + OCWW2;
    case 22: return g_wbuf + OCOVW1;
    case 23: return g_wbuf + OCOVW2;
    case 24: return g_wbuf + OCRW2;
    default: return nullptr;
  }
}

// ---------------- helpers ----------------
__device__ __forceinline__ float b2f(unsigned short u){
  unsigned int x = ((unsigned int)u) << 16;
  return __builtin_bit_cast(float, x);
}
__device__ __forceinline__ unsigned short f2b(float f){
  unsigned int u = __builtin_bit_cast(unsigned int, f);
  u += 0x7FFFu + ((u >> 16) & 1u);
  return (unsigned short)(u >> 16);
}
__device__ __forceinline__ float ldmix(const void* p, size_t i){
  return g_isf32 ? ((const float*)p)[i] : b2f(((const unsigned short*)p)[i]);
}
__device__ __forceinline__ float ldsel(bool f32, const void* p, size_t i){
  return f32 ? ((const float*)p)[i] : b2f(((const unsigned short*)p)[i]);
}
__device__ __forceinline__ float sigm(float x){ return 1.f/(1.f + __expf(-x)); }
__device__ __forceinline__ float tanh_f(float x){ float e = __expf(2.f*x); return 1.f - 2.f/(e + 1.f); }

// plain (L2-cached) direct-to-LDS 16B copy — used by GEMMs on read-once data
__device__ __forceinline__ void gld16(const unsigned short* g, unsigned short* l){
  __builtin_amdgcn_global_load_lds(
      (__attribute__((address_space(1))) void*)(uintptr_t)g,
      (__attribute__((address_space(3))) void*)l,
      16, 0, 0);
}
// SC1 (agent-coherent) direct-to-LDS 16B copy — bypasses the stale per-XCD L2
// and reads the coherent point (mall). CPol bit4 = SC1 on gfx940+.
__device__ __forceinline__ void gld16c(const unsigned short* g, unsigned short* l){
  __builtin_amdgcn_global_load_lds(
      (__attribute__((address_space(1))) void*)(uintptr_t)g,
      (__attribute__((address_space(3))) void*)l,
      16, 0, 16);
}

// ---------------- dtype detect (+ per-launch flag-epoch bump) ----------------
__global__ __launch_bounds__(256) void detect_dtype(const unsigned short* x){
  __shared__ int cnt;
  if (threadIdx.x == 0) cnt = 0;
  __syncthreads();
  int c = 0;
  for (int i = threadIdx.x; i < 4096; i += 256){
    float f = b2f(x[2*i]);
    if (!(fabsf(f) < 1e10f)) c++;
  }
  atomicAdd(&cnt, c);
  __syncthreads();
  if (threadIdx.x == 0){
    g_isf32 = (cnt > 64) ? 1 : 0;
    g_fepoch += 512;   // > max per-launch flag advance (TSTEPS+2), keeps epochs monotonic
  }
}

// ---------------- convert 14 arrays into g_wbuf (bf16) ----------------
__global__ __launch_bounds__(256) void cvt_all(
    const void* s0, const void* s1, const void* s2, const void* s3,
    const void* s4, const void* s5, const void* s6, const void* s7,
    const void* s8, const void* s9, const void* s10, const void* s11,
    const void* s12, const void* s13)
{
  const void* src; size_t off; int n;
  switch (blockIdx.y){
    case 0:  src=s0;  off=OX;     n=TOK*OBSD;  break;
    case 1:  src=s1;  off=OCOVH;  n=TOK*NACT;  break;
    case 2:  src=s2;  off=OSNW1;  n=HIDD*OBSD; break;
    case 3:  src=s3;  off=OSNW2;  n=HIDD*HIDD; break;
    case 4:  src=s4;  off=OWIH;   n=4*HIDD*HIDD; break;
    case 5:  src=s5;  off=OWHH;   n=4*HIDD*HIDD; break;
    case 6:  src=s6;  off=OACW1;  n=HIDD*HIDD; break;
    case 7:  src=s7;  off=OCWW1;  n=HIDD*HIDD; break;
    case 8:  src=s8;  off=OCRW1;  n=HIDD*HIDD; break;
    case 9:  src=s9;  off=OACW2;  n=NACT*HIDD; break;
    case 10: src=s10; off=OCWW2;  n=NACT*HIDD; break;
    case 11: src=s11; off=OCOVW1; n=HIDD*NACT; break;
    case 12: src=s12; off=OCOVW2; n=NACT*HIDD; break;
    default: src=s13; off=OCRW2;  n=HIDD;      break;
  }
  const bool f32 = (g_isf32 != 0);
  unsigned short* dst = g_wbuf + off;
  const int stride = gridDim.x * 256;
  for (int i = blockIdx.x*256 + threadIdx.x; i < n; i += stride){
    float v = f32 ? ((const float*)src)[i] : b2f(((const unsigned short*)src)[i]);
    dst[i] = f2b(v);
  }
}

// ---------------- tiled MFMA GEMM: C = act(A @ W^T + bias) ----------------
// 2-phase double-buffered (T3-minimum): prefetch tile t+1 into buf^1 while the
// MFMA of tile t runs from buf; ONE vmcnt(0)+barrier per K-step.
// ablk: A is blocked [cb][row][16] (g_hid2). bmode: 3-way bias select by col/1024.
__global__ __launch_bounds__(256) void gemm_bt(
    int a_id, int lda, int ablk, int w_id, int K,
    const void* __restrict__ b1, const void* __restrict__ b2, const void* __restrict__ b3,
    int bmode, int c_id, int ldc, int act, int cmode)
{
  __shared__ unsigned short sA[2][128*32];
  __shared__ unsigned short sB[2][128*32];
  const unsigned short* A = dev_buf(a_id);
  const unsigned short* W = dev_buf(w_id);
  void* C = dev_buf(c_id);

  const int tid  = threadIdx.x;
  const int wv   = tid >> 6, ln = tid & 63;
  const int quad = ln >> 4, l16 = ln & 15;
  const long bm = (long)blockIdx.y * 128, bn = (long)blockIdx.x * 128;
  const int wr = (wv >> 1) * 64, wc = (wv & 1) * 64;

  const f32x4 zf = {0.f, 0.f, 0.f, 0.f};
  f32x4 acc[4][4];
#pragma unroll
  for (int i = 0; i < 4; i++)
#pragma unroll
    for (int j = 0; j < 4; j++) acc[i][j] = zf;

  const int srow = wv*32 + (ln >> 2);
  const int scol = (ln & 3) * 8;
  const unsigned short* gA = A + (bm + srow)*(long)lda + scol;
  const unsigned short* gB = W + (bn + srow)*(long)K   + scol;
  const int lofs = (wv*32)*32;

  // stage K-tile (k0) into buffer b
  auto STAGE = [&](int k0, int b){
    unsigned short* lA = &sA[b][lofs];
    unsigned short* lB = &sB[b][lofs];
    if (ablk){
      const int kk = k0 + scol;
      const long cbase = (long)(kk >> 4) * ((long)TOK*16) + (kk & 15);
      gld16(A + cbase + (bm + srow)*16,      lA);
      gld16(A + cbase + (bm + srow + 16)*16, lA + 16*32);
    } else {
      gld16(gA + k0,                lA);
      gld16(gA + k0 + 16*(long)lda, lA + 16*32);
    }
    gld16(gB + k0,               lB);
    gld16(gB + k0 + 16*(long)K,  lB + 16*32);
  };

  STAGE(0, 0);
  asm volatile("s_waitcnt vmcnt(0)" ::: "memory");
  __syncthreads();

  int cur = 0;
  for (int k0 = 0; k0 < K; k0 += 32){
    if (k0 + 32 < K) STAGE(k0 + 32, cur ^ 1);   // prefetch next tile (overlaps MFMA)
    bf16x8 af[4], bfr[4];
#pragma unroll
    for (int i = 0; i < 4; i++) af[i]  = *(const bf16x8*)&sA[cur][(wr + 16*i + l16)*32 + quad*8];
#pragma unroll
    for (int j = 0; j < 4; j++) bfr[j] = *(const bf16x8*)&sB[cur][(wc + 16*j + l16)*32 + quad*8];
#pragma unroll
    for (int i = 0; i < 4; i++)
#pragma unroll
      for (int j = 0; j < 4; j++)
        acc[i][j] = __builtin_amdgcn_mfma_f32_16x16x32_bf16(af[i], bfr[j], acc[i][j], 0, 0, 0);
    asm volatile("s_waitcnt vmcnt(0)" ::: "memory");
    __syncthreads();
    cur ^= 1;
  }

#pragma unroll
  for (int j = 0; j < 4; j++){
    const long col = bn + wc + 16*j + l16;
    float bb;
    if (bmode){
      const void* bp = (col < 1024) ? b1 : (col < 2048) ? b2 : b3;
      bb = ldmix(bp, col & 1023);
    } else {
      bb = (b1 ? ldmix(b1, col) : 0.f) + (b2 ? ldmix(b2, col) : 0.f);
    }
#pragma unroll
    for (int i = 0; i < 4; i++){
#pragma unroll
      for (int r = 0; r < 4; r++){
        const long row = bm + wr + 16*i + quad*4 + r;   // C/D: col=lane&15, row=quad*4+reg
        float v = acc[i][j][r] + bb;
        if (act) v = tanh_f(v);
        if (cmode) ((float*)C)[row*(long)ldc + col] = v;
        else ((unsigned short*)C)[row*(long)ldc + col] = f2b(v);
      }
    }
  }
}

// ---------------- fused head GEMMs: aco | cwo | covo in ONE launch ----------------
// grid (3, TOK/128): blockIdx.x selects the head (3x parallelism for the
// latency-bound N=128 tails, one launch instead of three).
// 0: aco  = t3[:,0:1024]   @ acw2^T  + b_ac
// 1: cwo  = t3[:,1024:2048]@ cww2^T  + b_cw
// 2: covo = hid1           @ covw2^T + b_cov   (hid1 = tanh(cov_hist@cov_w1+b))
__global__ __launch_bounds__(256) void gemm_heads(
    const void* __restrict__ b_ac, const void* __restrict__ b_cw,
    const void* __restrict__ b_cov)
{
  __shared__ unsigned short sA[2][128*32];
  __shared__ unsigned short sB[2][128*32];

  const int which = blockIdx.x;
  const unsigned short* A; const unsigned short* W; unsigned short* C;
  const void* bias; long lda;
  if (which == 0){ A = g_t3;        lda = 3072; W = g_wbuf + OACW2;  C = g_aco;  bias = b_ac; }
  else if (which == 1){ A = g_t3 + 1024; lda = 3072; W = g_wbuf + OCWW2;  C = g_cwo;  bias = b_cw; }
  else { A = g_hid1;      lda = 1024; W = g_wbuf + OCOVW2; C = g_covo; bias = b_cov; }
  const int K = HIDD;

  const int tid  = threadIdx.x;
  const int wv   = tid >> 6, ln = tid & 63;
  const int quad = ln >> 4, l16 = ln & 15;
  const long bm = (long)blockIdx.y * 128;
  const int wr = (wv >> 1) * 64, wc = (wv & 1) * 64;

  const f32x4 zf = {0.f, 0.f, 0.f, 0.f};
  f32x4 acc[4][4];
#pragma unroll
  for (int i = 0; i < 4; i++)
#pragma unroll
    for (int j = 0; j < 4; j++) acc[i][j] = zf;

  const int srow = wv*32 + (ln >> 2);
  const int scol = (ln & 3) * 8;
  const unsigned short* gA = A + (bm + srow)*lda + scol;
  const unsigned short* gB = W + (long)srow*K    + scol;
  const int lofs = (wv*32)*32;

  auto STAGE = [&](int k0, int b){
    unsigned short* lA = &sA[b][lofs];
    unsigned short* lB = &sB[b][lofs];
    gld16(gA + k0,            lA);
    gld16(gA + k0 + 16*lda,   lA + 16*32);
    gld16(gB + k0,            lB);
    gld16(gB + k0 + 16*K,     lB + 16*32);
  };

  STAGE(0, 0);
  asm volatile("s_waitcnt vmcnt(0)" ::: "memory");
  __syncthreads();

  int cur = 0;
  for (int k0 = 0; k0 < K; k0 += 32){
    if (k0 + 32 < K) STAGE(k0 + 32, cur ^ 1);
    bf16x8 af[4], bfr[4];
#pragma unroll
    for (int i = 0; i < 4; i++) af[i]  = *(const bf16x8*)&sA[cur][(wr + 16*i + l16)*32 + quad*8];
#pragma unroll
    for (int j = 0; j < 4; j++) bfr[j] = *(const bf16x8*)&sB[cur][(wc + 16*j + l16)*32 + quad*8];
#pragma unroll
    for (int i = 0; i < 4; i++)
#pragma unroll
      for (int j = 0; j < 4; j++)
        acc[i][j] = __builtin_amdgcn_mfma_f32_16x16x32_bf16(af[i], bfr[j], acc[i][j], 0, 0, 0);
    asm volatile("s_waitcnt vmcnt(0)" ::: "memory");
    __syncthreads();
    cur ^= 1;
  }

#pragma unroll
  for (int j = 0; j < 4; j++){
    const int col = wc + 16*j + l16;                  // 0..127
    float bb = ldmix(bias, col);
#pragma unroll
    for (int i = 0; i < 4; i++){
#pragma unroll
      for (int r = 0; r < 4; r++){
        const long row = bm + wr + 16*i + quad*4 + r;
        C[row*(long)NACT + col] = f2b(acc[i][j][r] + bb);
      }
    }
  }
}

// ---------------- persistent LSTM scan: 4 independent batch-groups x 64 shards ------
// (unchanged from R3 — verified structure)
__global__ __launch_bounds__(256, 1) void lstm_scan(
    const void* __restrict__ done_p,
    const void* __restrict__ h0_p,
    const void* __restrict__ c0_p)
{
  __shared__ __align__(16) unsigned short sH[16384];
  float* sPf = (float*)sH;     // slab view: wave w2 at float offset w2*2048

  const int tid  = threadIdx.x;
  const int wv   = tid >> 6, ln = tid & 63;
  const int quad = ln >> 4, l16 = ln & 15;
  const int cbid = blockIdx.x;
  const int grp  = cbid >> 6;          // batch-group: rows [grp*16, +16)
  const int shrd = cbid & 63;          // col-shard:  cols [shrd*16, +16)
  const int rr0  = grp * 16;
  const int cc0  = shrd * 16;
  const int row  = tid >> 4;           // gate-phase batch row (0..15)
  const int col  = tid & 15;           // gate-phase col (0..15)
  const bool isf32 = (g_isf32 != 0);
  const unsigned fbase = g_fepoch;     // per-launch monotonic epoch base
  const int fidx = grp*64 + wv*16 + (ln & 15);   // this wave's 16 producer flags

  // cell state: one element per thread
  float cst = ldsel(isf32, c0_p, (size_t)(rr0 + row)*HIDD + cc0 + col);

  // h0 -> parity-0 slot (own tile), masked by done[0], packed pairs, sc1
  {
    float d0 = ldsel(isf32, done_p, rr0 + row);
    float h0 = (d0 != 0.f) ? 0.f : ldsel(isf32, h0_p, (size_t)(rr0 + row)*HIDD + cc0 + col);
    unsigned short hu = f2b(h0);
    unsigned hv = (unsigned)hu | ((unsigned)(unsigned short)__shfl_down((int)hu, 1, 64) << 16);
    if ((ln & 1) == 0){
      unsigned* hp = (unsigned*)&g_hp2[grp*16384 + shrd*256 + row*16 + col];
      __hip_atomic_store(hp, hv, __ATOMIC_RELAXED, __HIP_MEMORY_SCOPE_AGENT);
    }
  }

  // preload w_hh K-quarter for all 4 gates: wreg[g][i], k = wv*256 + i*32 + quad*8
  const unsigned short* wbase = g_wbuf + OWHH;
  bf16x8 wreg[4][8];
#pragma unroll
  for (int g = 0; g < 4; g++)
#pragma unroll
    for (int i = 0; i < 8; i++)
      wreg[g][i] = *(const bf16x8*)&wbase[(size_t)(g*HIDD + cc0 + l16)*HIDD + wv*256 + i*32 + quad*8];

  // prefetch step-0 inputs into registers (4 gate-preacts per thread)
  float xgv0, xgv1, xgv2, xgv3;
  {
    const float* xr = &g_xgf[(size_t)(rr0 + row)*4096 + cc0 + col];
    xgv0 = xr[0]; xgv1 = xr[1024]; xgv2 = xr[2048]; xgv3 = xr[3072];
  }
  float dcur = ldsel(isf32, done_p, rr0 + row);             // done[0]
  float dnxt = ldsel(isf32, done_p, BATCH + rr0 + row);     // done[1]

  // publish h0: __syncthreads drains vmcnt (sc1 stores ack'd at the mall),
  // then one RELAXED flag store — no release fence, no buffer_wbl2.
  __syncthreads();
  if (tid == 0)
    __hip_atomic_store(&g_flags[cbid], fbase + 1, __ATOMIC_RELAXED, __HIP_MEMORY_SCOPE_AGENT);

  const f32x4 zf = {0.f, 0.f, 0.f, 0.f};

#define MFMA_ITER(ii, NW)                                                        \
  {                                                                              \
    asm volatile("s_waitcnt vmcnt(" #NW ")" ::: "memory");                       \
    bf16x8 af = *(const bf16x8*)(hq + (ii)*512);                                 \
    _Pragma("unroll")                                                            \
    for (int g = 0; g < 4; g++)                                                  \
      acc[g] = __builtin_amdgcn_mfma_f32_16x16x32_bf16(af, wreg[g][ii],          \
                                                       acc[g], 0, 0, 0);         \
  }

  for (int s = 0; s < TSTEPS; s++){
    // drain ALL prior vmem (xg prefetch, h/hid2 stores) BEFORE the poll:
    // their latency overlaps the producer wait, and the staged-load vmcnt
    // counting below stays exact.
    asm volatile("s_waitcnt vmcnt(0)" ::: "memory");

    // per-wave wait on this wave's 16 producer shards (within our group).
    {
      const unsigned tgt = fbase + (unsigned)s + 1u;
      unsigned f = __hip_atomic_load(&g_flags[fidx], __ATOMIC_RELAXED, __HIP_MEMORY_SCOPE_AGENT);
      while (!__all((int)(f >= tgt))){
        __builtin_amdgcn_s_sleep(1);
        f = __hip_atomic_load(&g_flags[fidx], __ATOMIC_RELAXED, __HIP_MEMORY_SCOPE_AGENT);
      }
    }
    asm volatile("s_waitcnt vmcnt(0)" ::: "memory");   // poll loads drained

    const unsigned short* hb = g_hp2 + (s & 1)*65536 + grp*16384;
    unsigned short*       hn = g_hp2 + ((s + 1) & 1)*65536 + grp*16384;

    // stage this wave's 8 KB h K-quarter (16 shards x 512B) into LDS:
    // 8 x 1KB SC1 direct-to-LDS loads, zero VGPR cost.
    {
      const unsigned short* src = hb + wv*4096 + ln*8;
      unsigned short* dstb = sH + wv*4096;     // wave-uniform base; HW adds lane*16B
#pragma unroll
      for (int c2 = 0; c2 < 8; c2++)
        gld16c(src + c2*512, dstb + c2*512);
    }

    // MFMA phase interleaved with the fill: iteration i consumes load i.
    const unsigned short* hq = sH + wv*4096 + (quad >> 1)*256 + l16*16 + (quad & 1)*8;
    f32x4 acc[4];   // [gate]
#pragma unroll
    for (int g = 0; g < 4; g++) acc[g] = zf;

    MFMA_ITER(0, 7)
    MFMA_ITER(1, 6)
    MFMA_ITER(2, 5)
    MFMA_ITER(3, 4)
    MFMA_ITER(4, 3)
    MFMA_ITER(5, 2)
    MFMA_ITER(6, 1)
    MFMA_ITER(7, 0)

    // write gate-partial slabs into THIS wave's own (consumed) LDS region
#pragma unroll
    for (int g = 0; g < 4; g++)
#pragma unroll
      for (int r = 0; r < 4; r++)
        sPf[wv*2048 + g*320 + (quad*4 + r)*20 + l16] = acc[g][r];
    __syncthreads();

    // gate phase: sum 4 K-partials per gate, then LSTM cell update (1 elem/thread)
    float pg0 = 0.f, pg1 = 0.f, pg2 = 0.f, pg3 = 0.f;
#pragma unroll
    for (int w2 = 0; w2 < 4; w2++){
      const float* sb = &sPf[w2*2048 + row*20 + col];
      pg0 += sb[0];
      pg1 += sb[320];
      pg2 += sb[640];
      pg3 += sb[960];
    }
    const bool last = (s == TSTEPS-1);
    float iv = sigm (pg0 + xgv0);
    float fv = sigm (pg1 + xgv1);
    float gv = tanh_f(pg2 + xgv2);
    float ov = sigm (pg3 + xgv3);
    float cp = (dcur != 0.f) ? 0.f : cst;
    float c  = fv*cp + iv*gv;
    float h  = ov * tanh_f(c);
    cst = c;
    if (last){
      g_ht[(rr0 + row)*HIDD + cc0 + col] = h;
      g_ct[(rr0 + row)*HIDD + cc0 + col] = c;
    }
    // pack col-pairs and store next-h (pre-masked by done[s+1], sc1)
    unsigned short hu = f2b(h);
    unsigned hv = (unsigned)hu | ((unsigned)(unsigned short)__shfl_down((int)hu, 1, 64) << 16);
    unsigned hm = (dnxt != 0.f) ? 0u : hv;
    if ((ln & 1) == 0){
      unsigned* hnp = (unsigned*)&hn[shrd*256 + row*16 + col];
      __hip_atomic_store(hnp, hm, __ATOMIC_RELAXED, __HIP_MEMORY_SCOPE_AGENT);
    }

    // publish h_{s+1}: __syncthreads drains every wave's vmcnt (sc1 stores
    // retired at the coherent point), then one RELAXED flag store by tid0.
    __syncthreads();
    if (tid == 0)
      __hip_atomic_store(&g_flags[cbid], fbase + (unsigned)s + 2u, __ATOMIC_RELAXED, __HIP_MEMORY_SCOPE_AGENT);

    // off the critical path: blocked hidden store (read by later kernels)
    const int token = s*BATCH + rr0 + row;
    if ((ln & 1) == 0)
      *(unsigned*)&g_hid2[(size_t)shrd*((size_t)TOK*16) + (size_t)token*16 + col] = hv;

    // prefetch next step's inputs BEFORE the next poll (hidden under it)
    if (s + 1 < TSTEPS){
      const float* xr = &g_xgf[(size_t)((s+1)*BATCH + rr0 + row)*4096 + cc0 + col];
      xgv0 = xr[0]; xgv1 = xr[1024]; xgv2 = xr[2048]; xgv3 = xr[3072];
      dcur = dnxt;
      dnxt = (s + 2 < TSTEPS) ? ldsel(isf32, done_p, (size_t)(s+2)*BATCH + rr0 + row) : 0.f;
    }
  }
#undef MFMA_ITER
}

// ---------------- FINALIZE: only writer of d_out (fp32), full coverage ----------------
// Now also computes the value head (cr rowdot) inline — one launch fewer.
__global__ __launch_bounds__(256) void finalize(
    const int* __restrict__ action, const void* __restrict__ b_cr2,
    float* __restrict__ dout)
{
  int row = blockIdx.x*4 + (threadIdx.x >> 6);
  int ln  = threadIdx.x & 63;
  size_t base = (size_t)row * NACT;
  float l0 = b2f(g_aco[base+ln])    + b2f(g_cwo[base+ln])   *b2f(g_covo[base+ln]);
  float l1 = b2f(g_aco[base+64+ln]) + b2f(g_cwo[base+64+ln])*b2f(g_covo[base+64+ln]);
  float mx = fmaxf(l0, l1);
  for (int o = 32; o; o >>= 1) mx = fmaxf(mx, __shfl_xor(mx, o, 64));
  float e0 = __expf(l0 - mx), e1 = __expf(l1 - mx);
  float sm = e0 + e1;
  for (int o = 32; o; o >>= 1) sm += __shfl_xor(sm, o, 64);
  float inv = 1.f/sm, ls = __logf(sm);
  float p0 = e0*inv, p1 = e1*inv;
  float lp0 = l0 - mx - ls, lp1 = l1 - mx - ls;
  dout[O_PROBS + base + ln]      = p0;
  dout[O_PROBS + base + 64 + ln] = p1;
  float ent = -(p0*lp0 + p1*lp1);
  for (int o = 32; o; o >>= 1) ent += __shfl_xor(ent, o, 64);
  int a = action[row];
  float lpa = (a == ln) ? lp0 : (a == ln + 64) ? lp1 : 0.f;
  for (int o = 32; o; o >>= 1) lpa += __shfl_xor(lpa, o, 64);

  // value head: wave-per-row dot over cr slice of t3 (same order as old rowdot)
  const unsigned short* Acr = g_t3 + 2048;
  const unsigned short* wcr = g_wbuf + OCRW2;
  float sv = 0.f;
  for (int k = ln*8; k < HIDD; k += 512){
    bf16x8 av = *(const bf16x8*)&Acr[(size_t)row*3072 + k];
    bf16x8 wv8 = *(const bf16x8*)&wcr[k];
#pragma unroll
    for (int j = 0; j < 8; j++) sv += b2f((unsigned short)av[j]) * b2f((unsigned short)wv8[j]);
  }
  for (int o = 32; o; o >>= 1) sv += __shfl_xor(sv, o, 64);

  if (ln == 0){
    dout[O_LOGPA + row] = lpa;
    dout[O_ENT   + row] = ent;
    dout[O_VAL   + row] = sv + ldmix(b_cr2, 0);
  }
  int gtid = blockIdx.x*256 + threadIdx.x;
  if (gtid < BATCH*HIDD){
    dout[O_HT + gtid] = g_ht[gtid];
    dout[O_CT + gtid] = g_ct[gtid];
  }
}

// ---------------- host ----------------
extern "C" void kernel_launch(void* const* d_in, const int* in_sizes, int n_in,
                              void* d_out, int out_size, void* d_ws, size_t ws_size,
                              hipStream_t stream)
{
  (void)in_sizes; (void)n_in; (void)out_size; (void)d_ws; (void)ws_size;
  float* dout = (float*)d_out;

  hipLaunchKernelGGL(detect_dtype, dim3(1), dim3(256), 0, stream,
                     (const unsigned short*)d_in[0]);

  hipLaunchKernelGGL(cvt_all, dim3(512, 14), dim3(256), 0, stream,
                     d_in[0], d_in[2], d_in[6], d_in[8], d_in[10], d_in[11],
                     d_in[18], d_in[26], d_in[14], d_in[20], d_in[28],
                     d_in[22], d_in[24], d_in[16]);

  auto gemm = [&](int a_id, int lda, int ablk, int w_id, int K,
                  const void* b1, const void* b2, const void* b3, int bmode,
                  int c_id, int ldc, int N, int act, int cmode){
    hipLaunchKernelGGL(gemm_bt, dim3(N/128, TOK/128), dim3(256), 0, stream,
                       a_id, lda, ablk, w_id, K, b1, b2, b3, bmode,
                       c_id, ldc, act, cmode);
  };

  // perception MLP + hoisted input-gate GEMM
  gemm(11, OBSD, 0, 13, OBSD, d_in[7],  nullptr, nullptr, 0, 1, HIDD,   HIDD,   1, 0);
  gemm(1,  HIDD, 0, 14, HIDD, d_in[9],  nullptr, nullptr, 0, 2, HIDD,   HIDD,   1, 0);
  gemm(2,  HIDD, 0, 15, HIDD, d_in[12], d_in[13], nullptr, 0, 8, 4*HIDD, 4*HIDD, 0, 1);

  // sequential LSTM scan: 256 persistent WGs = 4 batch-groups x 64 shards
  hipLaunchKernelGGL(lstm_scan, dim3(256), dim3(256), 0, stream,
                     d_in[1], d_in[3], d_in[4]);

  // fused head hidden GEMM: t3 = tanh(hidden @ [ac|cw|cr]w1^T + b), N=3072, blocked A
  gemm(3, 3072, 1, 17, HIDD, d_in[19], d_in[27], d_in[15], 1, 4, 3*HIDD, 3*HIDD, 1, 0);
  // coverage perception GEMM (feeds covo)
  gemm(12, NACT, 0, 22, NACT, d_in[23], nullptr, nullptr, 0, 1, HIDD, HIDD, 1, 0);
  // fused output heads: aco | cwo | covo in one launch
  hipLaunchKernelGGL(gemm_heads, dim3(3, TOK/128), dim3(256), 0, stream,
                     d_in[21], d_in[29], d_in[25]);

  // single final writer of d_out (value head folded in)
  hipLaunchKernelGGL(finalize, dim3(TOK/4), dim3(256), 0, stream,
                     (const int*)d_in[5], d_in[17], dout);
}